// Round 1
// baseline (765.036 us; speedup 1.0000x reference)
//
#include <hip/hip_runtime.h>

#define N_NODES  100000
#define N_EDGES  1600000
#define NODE_DIM 64
#define EDGE_DIM 16
#define HIDDEN   64
#define AGG_BLOCKS 768           // 3 blocks/CU * 256 CUs
#define NB1 ((N_NODES + 255) / 256)   // 391 scan blocks

typedef __bf16 bf16x8 __attribute__((ext_vector_type(8)));
typedef unsigned short u16x8 __attribute__((ext_vector_type(8)));
typedef unsigned short u16x4 __attribute__((ext_vector_type(4)));
typedef float f32x4 __attribute__((ext_vector_type(4)));

__device__ __forceinline__ unsigned short f2bf(float f) {
    unsigned int u = __float_as_uint(f);
    u += 0x7FFFu + ((u >> 16) & 1u);          // RNE
    return (unsigned short)(u >> 16);
}

__device__ __forceinline__ float bf2f(unsigned short s) {
    return __uint_as_float((unsigned int)s << 16);
}

__device__ __forceinline__ bf16x8 lds_frag(const unsigned short* p) {
    return __builtin_bit_cast(bf16x8, *(const u16x8*)p);
}

__device__ __forceinline__ void cvt16v(unsigned short* dst,
                                       float4 f0, float4 f1, float4 f2, float4 f3) {
    u16x8 p0, p1;
    p0[0]=f2bf(f0.x); p0[1]=f2bf(f0.y); p0[2]=f2bf(f0.z); p0[3]=f2bf(f0.w);
    p0[4]=f2bf(f1.x); p0[5]=f2bf(f1.y); p0[6]=f2bf(f1.z); p0[7]=f2bf(f1.w);
    p1[0]=f2bf(f2.x); p1[1]=f2bf(f2.y); p1[2]=f2bf(f2.z); p1[3]=f2bf(f2.w);
    p1[4]=f2bf(f3.x); p1[5]=f2bf(f3.y); p1[6]=f2bf(f3.z); p1[7]=f2bf(f3.w);
    *(u16x8*)dst       = p0;
    *(u16x8*)(dst + 8) = p1;
}

__device__ __forceinline__ void cvt4v(unsigned short* dst, float4 f) {
    u16x4 p;
    p[0]=f2bf(f.x); p[1]=f2bf(f.y); p[2]=f2bf(f.z); p[3]=f2bf(f.w);
    *(u16x4*)dst = p;
}

// ---- prep: bf16 weights (transposed) + bf16 copy of x + dst-degree histogram ----
__global__ void prep_kernel(const float* __restrict__ W1, const float* __restrict__ W2,
                            const float* __restrict__ Wu, const float* __restrict__ x,
                            const int* __restrict__ ei,
                            unsigned short* __restrict__ W1t,   // [64][160], k>=144 zero
                            unsigned short* __restrict__ W2t,   // [64][64]
                            unsigned short* __restrict__ Wut,   // [64][128]
                            unsigned short* __restrict__ xb,    // [N][64] bf16
                            int* __restrict__ deg)
{
    int t = blockIdx.x * 256 + threadIdx.x;
    int stride = gridDim.x * 256;
    for (int i = t; i < N_NODES * 64 / 4; i += stride) {
        float4 f = ((const float4*)x)[i];
        cvt4v(&xb[i * 4], f);
    }
    for (int e = t; e < N_EDGES; e += stride)
        atomicAdd(&deg[ei[N_EDGES + e]], 1);
    for (int i = t; i < 64 * 160; i += stride) {
        int n = i / 160, k = i % 160;
        W1t[i] = (k < 144) ? f2bf(W1[k * 64 + n]) : (unsigned short)0;
    }
    for (int i = t; i < 64 * 64; i += stride) {
        int n = i / 64, k = i % 64;
        W2t[i] = f2bf(W2[k * 64 + n]);
    }
    for (int i = t; i < 64 * 128; i += stride) {
        int n = i / 128, k = i % 128;
        Wut[i] = f2bf(Wu[k * 64 + n]);
    }
}

// ---- CSR build: block scan -> block-sum scan -> add base, then fill edge list ----
__global__ void scan1_kernel(const int* __restrict__ deg, int* __restrict__ ofs,
                             int* __restrict__ bsum) {
    __shared__ int sh[256];
    int t = threadIdx.x, i = blockIdx.x * 256 + t;
    int v = (i < N_NODES) ? deg[i] : 0;
    sh[t] = v; __syncthreads();
    #pragma unroll
    for (int o = 1; o < 256; o <<= 1) {
        int add = (t >= o) ? sh[t - o] : 0;
        __syncthreads();
        sh[t] += add;
        __syncthreads();
    }
    if (i < N_NODES) ofs[i] = sh[t] - v;       // block-local exclusive
    if (t == 255) bsum[blockIdx.x] = sh[t];    // block total
}

__global__ void scan2_kernel(int* __restrict__ bsum) {
    __shared__ int sh[512];
    int t = threadIdx.x;
    int v = (t < NB1) ? bsum[t] : 0;
    sh[t] = v; __syncthreads();
    #pragma unroll
    for (int o = 1; o < 512; o <<= 1) {
        int add = (t >= o) ? sh[t - o] : 0;
        __syncthreads();
        sh[t] += add;
        __syncthreads();
    }
    if (t < NB1) bsum[t] = sh[t] - v;          // exclusive block bases
}

__global__ void scan3_kernel(int* __restrict__ ofs, const int* __restrict__ bsum,
                             int* __restrict__ cur) {
    int t = threadIdx.x, i = blockIdx.x * 256 + t;
    if (i < N_NODES) {
        int o = ofs[i] + bsum[blockIdx.x];
        ofs[i] = o;
        cur[i] = o;
    }
}

__global__ void fill_kernel(const int* __restrict__ ei, int* __restrict__ cur,
                            long long* __restrict__ elist) {
    int idx = blockIdx.x * 256 + threadIdx.x;
    int stride = gridDim.x * 256;
    for (int e = idx; e < N_EDGES; e += stride) {
        int s = ei[e];
        int d = ei[N_EDGES + e];
        int pos = atomicAdd(&cur[d], 1);
        elist[pos] = ((long long)e << 32) | (unsigned int)s;  // hi: edge id, lo: src
    }
}

// LDS strides (elems): Ain 168 (row 336B = 84dw, 84%32=20 -> 2-way, free)
// W1 164; H 72.
#define SA  168
#define SW1 164
#define SH  72
#define WAVE_LDS (16*SA*2 + 16*SH*2)   // 7680 B per wave

// ---- gather-side aggregation: one wave per destination node, zero atomics ----
__global__ __launch_bounds__(256, 3) void agg_kernel(
    const unsigned short* __restrict__ xb,
    const float* __restrict__ ea,
    const long long* __restrict__ elist,
    const int* __restrict__ ofs,
    const int* __restrict__ deg,
    const unsigned short* __restrict__ W1t,
    const unsigned short* __restrict__ W2t,
    const float* __restrict__ b1,
    const float* __restrict__ b2,
    unsigned short* __restrict__ agg)   // [N][64] bf16, count-normalized
{
    __shared__ __align__(16) unsigned short sW1[64 * SW1];
    __shared__ __align__(16) unsigned char  sAH[4 * WAVE_LDS];

    const int t    = threadIdx.x;
    const int lane = t & 63;
    const int w    = t >> 6;

    // ---- stage W1 once per block ----
    #pragma unroll
    for (int i = 0; i < 5; i++) {
        int c = t + i * 256;
        int n = c / 20, k8 = c % 20;
        *(u16x8*)&sW1[n * SW1 + k8 * 8] = *(const u16x8*)&W1t[c * 8];
    }
    __syncthreads();                     // the only block-wide barrier

    unsigned short* myAin = (unsigned short*)(sAH + w * WAVE_LDS);
    unsigned short* myH   = (unsigned short*)(sAH + w * WAVE_LDS + 16 * SA * 2);

    if (lane < 16) {                     // zero the K-pad once
        u16x8 z = {0,0,0,0,0,0,0,0};
        *(u16x8*)&myAin[lane * SA + 144] = z;
        *(u16x8*)&myAin[lane * SA + 152] = z;
    }

    const int col = lane & 15;
    const int kq  = lane >> 4;
    const int el  = lane >> 2;
    const int q   = lane & 3;

    // ---- per-lane constants ----
    float b1r[4], b2r[4];
    u16x8 w2f[8];
    #pragma unroll
    for (int ct = 0; ct < 4; ct++) {
        b1r[ct] = b1[ct * 16 + col];
        b2r[ct] = b2[ct * 16 + col];
        #pragma unroll
        for (int ks = 0; ks < 2; ks++)
            w2f[ks * 4 + ct] = *(const u16x8*)&W2t[(ct * 16 + col) * 64 + ks * 32 + kq * 8];
    }

    const int TW = AGG_BLOCKS * 4;
    for (int n = blockIdx.x * 4 + w; n < N_NODES; n += TW) {
        const int dg = deg[n];
        if (dg == 0) {
            agg[(size_t)n * 64 + lane] = 0;    // coalesced 128B zero row
            continue;
        }
        const int base = ofs[n];
        // dst-node row: shared by every edge of this node
        const u16x8* pd = (const u16x8*)(xb + (size_t)n * 64);
        const u16x8 d0 = pd[2 * q], d1 = pd[2 * q + 1];

        float aggv[4] = {0.f, 0.f, 0.f, 0.f};

        for (int g0 = 0; g0 < dg; g0 += 16) {
            const int rem = (dg - g0 < 16) ? (dg - g0) : 16;

            // ---- gather this group's edges (pad slots read row 0, masked later) ----
            long long se = 0;
            if (el < rem) se = elist[base + g0 + el];
            const int srci = (int)(se & 0xffffffffLL);
            const int eid  = (int)(se >> 32);
            const u16x8* ps = (const u16x8*)(xb + (size_t)srci * 64);
            u16x8 s0 = ps[2 * q], s1 = ps[2 * q + 1];
            float4 fe = ((const float4*)ea)[(size_t)eid * 4 + q];

            unsigned short* row = myAin + el * SA;
            *(u16x8*)(row + q * 16)          = s0;
            *(u16x8*)(row + q * 16 + 8)      = s1;
            *(u16x8*)(row + 64 + q * 16)     = d0;
            *(u16x8*)(row + 64 + q * 16 + 8) = d1;
            cvt4v(&row[128 + q * 4], fe);
            __builtin_amdgcn_wave_barrier();

            // ---- GEMM1: 16x160 @ 160x64 ----
            f32x4 acc[4] = {{0,0,0,0},{0,0,0,0},{0,0,0,0},{0,0,0,0}};
            #pragma unroll
            for (int ks = 0; ks < 5; ks++) {
                int ko = ks * 32 + kq * 8;
                bf16x8 a = lds_frag(&myAin[col * SA + ko]);
                #pragma unroll
                for (int ct = 0; ct < 4; ct++) {
                    bf16x8 b = lds_frag(&sW1[(ct * 16 + col) * SW1 + ko]);
                    acc[ct] = __builtin_amdgcn_mfma_f32_16x16x32_bf16(a, b, acc[ct], 0, 0, 0);
                }
            }
            #pragma unroll
            for (int ct = 0; ct < 4; ct++) {
                #pragma unroll
                for (int r = 0; r < 4; r++)
                    myH[(kq * 4 + r) * SH + ct * 16 + col] =
                        f2bf(fmaxf(acc[ct][r] + b1r[ct], 0.0f));
            }
            __builtin_amdgcn_wave_barrier();

            // ---- GEMM2: 16x64 @ 64x64 (B in registers) ----
            f32x4 m[4] = {{0,0,0,0},{0,0,0,0},{0,0,0,0},{0,0,0,0}};
            #pragma unroll
            for (int ks = 0; ks < 2; ks++) {
                int ko = ks * 32 + kq * 8;
                bf16x8 a = lds_frag(&myH[col * SH + ko]);
                #pragma unroll
                for (int ct = 0; ct < 4; ct++)
                    m[ct] = __builtin_amdgcn_mfma_f32_16x16x32_bf16(
                        a, __builtin_bit_cast(bf16x8, w2f[ks * 4 + ct]), m[ct], 0, 0, 0);
            }
            __builtin_amdgcn_wave_barrier();   // LDS reads done before next commit

            // ---- in-register row reduction (mask pad rows); +b2 per valid row ----
            #pragma unroll
            for (int ct = 0; ct < 4; ct++) {
                float ssum = 0.0f;
                #pragma unroll
                for (int r = 0; r < 4; r++) {
                    float v = m[ct][r] + b2r[ct];
                    ssum += ((kq * 4 + r) < rem) ? v : 0.0f;
                }
                ssum += __shfl_xor(ssum, 16);  // fold kq bit 0
                ssum += __shfl_xor(ssum, 32);  // fold kq bit 1
                aggv[ct] += ssum;              // all lanes: sum for col ct*16+col
            }
        }

        // lane kq holds aggv[kq] for col kq*16+col == lane -> coalesced 128B store
        const float scale = 1.0f / ((float)dg + 1e-6f);
        float vout = (kq == 0) ? aggv[0] : (kq == 1) ? aggv[1]
                   : (kq == 2) ? aggv[2] : aggv[3];
        agg[(size_t)n * 64 + lane] = f2bf(vout * scale);
    }
}

// ---- node update: [64 nodes x 128] x [128 x 64] per block, coalesced rows ----
#define NSA 136
__global__ __launch_bounds__(256, 4) void node_kernel(
    const float* __restrict__ x,
    const unsigned short* __restrict__ agg,   // bf16, already normalized
    const unsigned short* __restrict__ Wut,
    const float* __restrict__ bu,
    float* __restrict__ out)
{
    __shared__ __align__(16) unsigned short sA [64 * NSA];
    __shared__ __align__(16) unsigned short sWu[64 * NSA];
    const int t = threadIdx.x, lane = t & 63, w = t >> 6;
    const int n0 = blockIdx.x * 64;

    #pragma unroll
    for (int i = 0; i < 4; i++) {
        int c = t + i * 256;
        int n = c / 16, k8 = c % 16;
        *(u16x8*)&sWu[n * NSA + k8 * 8] = *(const u16x8*)&Wut[c * 8];
    }
    {
        const int nl = t >> 2, q = t & 3;
        const int n = n0 + nl;
        unsigned short* row = sA + nl * NSA;
        if (n < N_NODES) {
            const float4* px = (const float4*)(x + (size_t)n * 64);
            cvt16v(row + q * 16, px[q*4], px[q*4+1], px[q*4+2], px[q*4+3]);
            const u16x8* pa = (const u16x8*)(agg + (size_t)n * 64);
            *(u16x8*)(row + 64 + q * 16)     = pa[2 * q];
            *(u16x8*)(row + 64 + q * 16 + 8) = pa[2 * q + 1];
        } else {
            u16x8 z = {0,0,0,0,0,0,0,0};
            *(u16x8*)&row[q * 16]          = z;
            *(u16x8*)&row[q * 16 + 8]      = z;
            *(u16x8*)&row[64 + q * 16]     = z;
            *(u16x8*)&row[64 + q * 16 + 8] = z;
        }
    }
    __syncthreads();

    const int col = lane & 15, kq = lane >> 4;
    const int arow = w * 16 + col;
    f32x4 acc[4] = {{0,0,0,0},{0,0,0,0},{0,0,0,0},{0,0,0,0}};
    #pragma unroll
    for (int ks = 0; ks < 4; ks++) {
        int ko = ks * 32 + kq * 8;
        bf16x8 a = lds_frag(&sA[arow * NSA + ko]);
        #pragma unroll
        for (int ct = 0; ct < 4; ct++) {
            bf16x8 b = lds_frag(&sWu[(ct * 16 + col) * NSA + ko]);
            acc[ct] = __builtin_amdgcn_mfma_f32_16x16x32_bf16(a, b, acc[ct], 0, 0, 0);
        }
    }
    #pragma unroll
    for (int ct = 0; ct < 4; ct++) {
        float bb = bu[ct * 16 + col];
        #pragma unroll
        for (int r = 0; r < 4; r++) {
            int row = w * 16 + kq * 4 + r;
            int n = n0 + row;
            if (n < N_NODES) {
                int c2 = ct * 16 + col;
                float xa = x[(size_t)n * 64 + c2];          // exact fp32 residual
                out[(size_t)n * 64 + c2] = xa + fmaxf(acc[ct][r] + bb, 0.0f);
            }
        }
    }
}

extern "C" void kernel_launch(void* const* d_in, const int* in_sizes, int n_in,
                              void* d_out, int out_size, void* d_ws, size_t ws_size,
                              hipStream_t stream) {
    const float* x  = (const float*)d_in[0];
    const int*   ei = (const int*)  d_in[1];
    const float* ea = (const float*)d_in[2];
    const float* W1 = (const float*)d_in[3];
    const float* b1 = (const float*)d_in[4];
    const float* W2 = (const float*)d_in[5];
    const float* b2 = (const float*)d_in[6];
    const float* Wu = (const float*)d_in[7];
    const float* bu = (const float*)d_in[8];
    float* out = (float*)d_out;

    // workspace layout (~40 MB total)
    unsigned short* agg = (unsigned short*)d_ws;                 // [N][64] bf16
    int* deg  = (int*)(agg + (size_t)N_NODES * HIDDEN);          // [N]
    int* ofs  = deg + N_NODES;                                   // [N]
    int* cur  = ofs + N_NODES;                                   // [N]
    int* bsum = cur + N_NODES;                                   // [512]
    long long* elist = (long long*)(bsum + 512);                 // [E] (eid<<32)|src
    unsigned short* W1t = (unsigned short*)(elist + N_EDGES);    // [64][160]
    unsigned short* W2t = W1t + 64 * 160;                        // [64][64]
    unsigned short* Wut = W2t + 64 * 64;                         // [64][128]
    unsigned short* xb  = Wut + 64 * 128;                        // [N][64] bf16

    hipMemsetAsync(deg, 0, (size_t)N_NODES * sizeof(int), stream);

    prep_kernel<<<512, 256, 0, stream>>>(W1, W2, Wu, x, ei, W1t, W2t, Wut, xb, deg);
    scan1_kernel<<<NB1, 256, 0, stream>>>(deg, ofs, bsum);
    scan2_kernel<<<1, 512, 0, stream>>>(bsum);
    scan3_kernel<<<NB1, 256, 0, stream>>>(ofs, bsum, cur);
    fill_kernel<<<1024, 256, 0, stream>>>(ei, cur, elist);
    agg_kernel<<<AGG_BLOCKS, 256, 0, stream>>>(xb, ea, elist, ofs, deg,
                                               W1t, W2t, b1, b2, agg);
    node_kernel<<<(N_NODES + 63) / 64, 256, 0, stream>>>(x, agg, Wut, bu, out);
}

// Round 3
// 764.587 us; speedup vs baseline: 1.0006x; 1.0006x over previous
//
#include <hip/hip_runtime.h>

#define N_NODES  100000
#define N_EDGES  1600000
#define NODE_DIM 64
#define EDGE_DIM 16
#define HIDDEN   64
#define AGG_BLOCKS 768           // 3 blocks/CU * 256 CUs
#define NB1 ((N_NODES + 255) / 256)   // 391 scan blocks

typedef __bf16 bf16x8 __attribute__((ext_vector_type(8)));
typedef unsigned short u16x8 __attribute__((ext_vector_type(8)));
typedef unsigned short u16x4 __attribute__((ext_vector_type(4)));
typedef float f32x4 __attribute__((ext_vector_type(4)));

__device__ __forceinline__ unsigned short f2bf(float f) {
    unsigned int u = __float_as_uint(f);
    u += 0x7FFFu + ((u >> 16) & 1u);          // RNE
    return (unsigned short)(u >> 16);
}

__device__ __forceinline__ float bf2f(unsigned short s) {
    return __uint_as_float((unsigned int)s << 16);
}

__device__ __forceinline__ bf16x8 lds_frag(const unsigned short* p) {
    return __builtin_bit_cast(bf16x8, *(const u16x8*)p);
}

__device__ __forceinline__ void cvt16v(unsigned short* dst,
                                       float4 f0, float4 f1, float4 f2, float4 f3) {
    u16x8 p0, p1;
    p0[0]=f2bf(f0.x); p0[1]=f2bf(f0.y); p0[2]=f2bf(f0.z); p0[3]=f2bf(f0.w);
    p0[4]=f2bf(f1.x); p0[5]=f2bf(f1.y); p0[6]=f2bf(f1.z); p0[7]=f2bf(f1.w);
    p1[0]=f2bf(f2.x); p1[1]=f2bf(f2.y); p1[2]=f2bf(f2.z); p1[3]=f2bf(f2.w);
    p1[4]=f2bf(f3.x); p1[5]=f2bf(f3.y); p1[6]=f2bf(f3.z); p1[7]=f2bf(f3.w);
    *(u16x8*)dst       = p0;
    *(u16x8*)(dst + 8) = p1;
}

__device__ __forceinline__ void cvt4v(unsigned short* dst, float4 f) {
    u16x4 p;
    p[0]=f2bf(f.x); p[1]=f2bf(f.y); p[2]=f2bf(f.z); p[3]=f2bf(f.w);
    *(u16x4*)dst = p;
}

// ---- prep: bf16 weights (transposed) + bf16 copy of x + dst-degree histogram ----
__global__ void prep_kernel(const float* __restrict__ W1, const float* __restrict__ W2,
                            const float* __restrict__ Wu, const float* __restrict__ x,
                            const int* __restrict__ ei,
                            unsigned short* __restrict__ W1t,   // [64][160], k>=144 zero
                            unsigned short* __restrict__ W2t,   // [64][64]
                            unsigned short* __restrict__ Wut,   // [64][128]
                            unsigned short* __restrict__ xb,    // [N][64] bf16
                            int* __restrict__ deg)
{
    int t = blockIdx.x * 256 + threadIdx.x;
    int stride = gridDim.x * 256;
    for (int i = t; i < N_NODES * 64 / 4; i += stride) {
        float4 f = ((const float4*)x)[i];
        cvt4v(&xb[i * 4], f);
    }
    for (int e = t; e < N_EDGES; e += stride)
        atomicAdd(&deg[ei[N_EDGES + e]], 1);
    for (int i = t; i < 64 * 160; i += stride) {
        int n = i / 160, k = i % 160;
        W1t[i] = (k < 144) ? f2bf(W1[k * 64 + n]) : (unsigned short)0;
    }
    for (int i = t; i < 64 * 64; i += stride) {
        int n = i / 64, k = i % 64;
        W2t[i] = f2bf(W2[k * 64 + n]);
    }
    for (int i = t; i < 64 * 128; i += stride) {
        int n = i / 128, k = i % 128;
        Wut[i] = f2bf(Wu[k * 64 + n]);
    }
}

// ---- CSR build: block scan -> block-sum scan -> add base, then fill edge list ----
__global__ void scan1_kernel(const int* __restrict__ deg, int* __restrict__ ofs,
                             int* __restrict__ bsum) {
    __shared__ int sh[256];
    int t = threadIdx.x, i = blockIdx.x * 256 + t;
    int v = (i < N_NODES) ? deg[i] : 0;
    sh[t] = v; __syncthreads();
    #pragma unroll
    for (int o = 1; o < 256; o <<= 1) {
        int add = (t >= o) ? sh[t - o] : 0;
        __syncthreads();
        sh[t] += add;
        __syncthreads();
    }
    if (i < N_NODES) ofs[i] = sh[t] - v;       // block-local exclusive
    if (t == 255) bsum[blockIdx.x] = sh[t];    // block total
}

__global__ void scan2_kernel(int* __restrict__ bsum) {
    __shared__ int sh[512];
    int t = threadIdx.x;
    int v = (t < NB1) ? bsum[t] : 0;
    sh[t] = v; __syncthreads();
    #pragma unroll
    for (int o = 1; o < 512; o <<= 1) {
        int add = (t >= o) ? sh[t - o] : 0;
        __syncthreads();
        sh[t] += add;
        __syncthreads();
    }
    if (t < NB1) bsum[t] = sh[t] - v;          // exclusive block bases
}

__global__ void scan3_kernel(int* __restrict__ ofs, const int* __restrict__ bsum,
                             int* __restrict__ cur) {
    int t = threadIdx.x, i = blockIdx.x * 256 + t;
    if (i < N_NODES) {
        int o = ofs[i] + bsum[blockIdx.x];
        ofs[i] = o;
        cur[i] = o;
    }
    if (blockIdx.x == 0 && t == 0) {           // tail so (ofs[n], ofs[n+1]) always valid
        ofs[N_NODES]     = N_EDGES;
        ofs[N_NODES + 1] = N_EDGES;
    }
}

__global__ void fill_kernel(const int* __restrict__ ei, int* __restrict__ cur,
                            long long* __restrict__ elist) {
    int idx = blockIdx.x * 256 + threadIdx.x;
    int stride = gridDim.x * 256;
    if (idx < 16) elist[N_EDGES + idx] = 0;    // zero pad: unconditional group loads
    for (int e = idx; e < N_EDGES; e += stride) {
        int s = ei[e];
        int d = ei[N_EDGES + e];
        int pos = atomicAdd(&cur[d], 1);
        elist[pos] = ((long long)e << 32) | (unsigned int)s;  // hi: edge id, lo: src
    }
}

// LDS strides (elems): Ain 168 (row 336B = 84dw, 84%32=20 -> 2-way, free)
// W1 164; H 72.
#define SA  168
#define SW1 164
#define SH  72
#define WAVE_LDS (16*SA*2 + 16*SH*2)   // 7680 B per wave

// ---- gather-side aggregation: one wave per destination node, zero atomics,
// ---- 1-deep software pipeline (elist + gather prefetch across the GEMM phases) ----
__global__ __launch_bounds__(256, 3) void agg_kernel(
    const unsigned short* __restrict__ xb,
    const float* __restrict__ ea,
    const long long* __restrict__ elist,
    const int* __restrict__ ofs,              // N+2 entries, tail = E
    const unsigned short* __restrict__ W1t,
    const unsigned short* __restrict__ W2t,
    const float* __restrict__ b1,
    const float* __restrict__ b2,
    unsigned short* __restrict__ agg)   // [N][64] bf16, count-normalized (pre-zeroed)
{
    __shared__ __align__(16) unsigned short sW1[64 * SW1];
    __shared__ __align__(16) unsigned char  sAH[4 * WAVE_LDS];

    const int t    = threadIdx.x;
    const int lane = t & 63;
    const int w    = t >> 6;

    // ---- stage W1 once per block ----
    #pragma unroll
    for (int i = 0; i < 5; i++) {
        int c = t + i * 256;
        int n = c / 20, k8 = c % 20;
        *(u16x8*)&sW1[n * SW1 + k8 * 8] = *(const u16x8*)&W1t[c * 8];
    }
    __syncthreads();                     // the only block-wide barrier

    unsigned short* myAin = (unsigned short*)(sAH + w * WAVE_LDS);
    unsigned short* myH   = (unsigned short*)(sAH + w * WAVE_LDS + 16 * SA * 2);

    if (lane < 16) {                     // zero the K-pad once
        u16x8 z = {0,0,0,0,0,0,0,0};
        *(u16x8*)&myAin[lane * SA + 144] = z;
        *(u16x8*)&myAin[lane * SA + 152] = z;
    }

    const int col = lane & 15;
    const int kq  = lane >> 4;
    const int el  = lane >> 2;
    const int q   = lane & 3;

    // ---- per-lane constants ----
    float b1r[4], b2r[4];
    u16x8 w2f[8];
    #pragma unroll
    for (int ct = 0; ct < 4; ct++) {
        b1r[ct] = b1[ct * 16 + col];
        b2r[ct] = b2[ct * 16 + col];
        #pragma unroll
        for (int ks = 0; ks < 2; ks++)
            w2f[ks * 4 + ct] = *(const u16x8*)&W2t[(ct * 16 + col) * 64 + ks * 32 + kq * 8];
    }

    const int TW = AGG_BLOCKS * 4;

    // ---------- prologue: node A, lookahead node B meta, node C ofs-pair ----------
    int nodeA = blockIdx.x * 4 + w;           // < 3072 < N, in-bounds
    int baseA = ofs[nodeA];
    int dgA   = ofs[nodeA + 1] - baseA;
    while (dgA == 0 && nodeA < N_NODES) {     // ~never (P ~ e^-16); agg pre-zeroed
        nodeA += TW;
        if (nodeA < N_NODES) { baseA = ofs[nodeA]; dgA = ofs[nodeA + 1] - baseA; }
    }
    if (nodeA >= N_NODES) return;

    int nodeB = nodeA + TW;
    int baseB, dgB;
    {
        int ix = nodeB < N_NODES ? nodeB : N_NODES;
        baseB = ofs[ix];
        dgB   = ofs[ix + 1] - baseB;
        while (dgB == 0 && nodeB < N_NODES) {
            nodeB += TW;
            int ix2 = nodeB < N_NODES ? nodeB : N_NODES;
            baseB = ofs[ix2]; dgB = ofs[ix2 + 1] - baseB;
        }
    }
    int nodeC = nodeB + TW;
    int pC0, pC1;
    {
        int ix = nodeC < N_NODES ? nodeC : N_NODES;
        pC0 = ofs[ix]; pC1 = ofs[ix + 1];     // in flight until first node switch
    }

    // dst rows for A (resident) and B (prefetch)
    const u16x8* pdA = (const u16x8*)(xb + (size_t)nodeA * 64);
    u16x8 d0A = pdA[2 * q], d1A = pdA[2 * q + 1];
    int nbsB = nodeB < N_NODES ? nodeB : 0;
    const u16x8* pdB = (const u16x8*)(xb + (size_t)nbsB * 64);
    u16x8 d0B = pdB[2 * q], d1B = pdB[2 * q + 1];

    // first gather (item (A, group 0))
    long long se = elist[baseA + el];
    int srci = (int)(se & 0xffffffffLL), eid = (int)(se >> 32);
    const u16x8* ps = (const u16x8*)(xb + (size_t)srci * 64);
    u16x8 gx0 = ps[2 * q], gx1 = ps[2 * q + 1];
    float4 fe = ((const float4*)ea)[(size_t)eid * 4 + q];

    int g0 = 0;
    float aggv[4] = {0.f, 0.f, 0.f, 0.f};

    for (;;) {
        const int remv = dgA - g0;
        const int rem  = remv < 16 ? remv : 16;
        const bool last = (g0 + 16 >= dgA);

        // ---- issue next item's elist row (lands during commit+GEMM1) ----
        const int nb = last ? baseB : (baseA + g0 + 16);
        long long seN = elist[nb + el];        // padded array: unconditional

        // ---- commit current gather to LDS ----
        unsigned short* rowp = myAin + el * SA;
        *(u16x8*)(rowp + q * 16)          = gx0;
        *(u16x8*)(rowp + q * 16 + 8)      = gx1;
        *(u16x8*)(rowp + 64 + q * 16)     = d0A;
        *(u16x8*)(rowp + 64 + q * 16 + 8) = d1A;
        cvt4v(&rowp[128 + q * 4], fe);
        __builtin_amdgcn_wave_barrier();

        // ---- issue NEXT gather (overlaps GEMM1+GEMM2, consumed next commit) ----
        const int srciN = (int)(seN & 0xffffffffLL);
        const int eidN  = (int)(seN >> 32);
        const u16x8* psN = (const u16x8*)(xb + (size_t)srciN * 64);
        u16x8 gxN0 = psN[2 * q], gxN1 = psN[2 * q + 1];
        float4 feN = ((const float4*)ea)[(size_t)eidN * 4 + q];

        // ---- GEMM1: 16x160 @ 160x64 ----
        f32x4 acc[4] = {{0,0,0,0},{0,0,0,0},{0,0,0,0},{0,0,0,0}};
        #pragma unroll
        for (int ks = 0; ks < 5; ks++) {
            int ko = ks * 32 + kq * 8;
            bf16x8 a = lds_frag(&myAin[col * SA + ko]);
            #pragma unroll
            for (int ct = 0; ct < 4; ct++) {
                bf16x8 b = lds_frag(&sW1[(ct * 16 + col) * SW1 + ko]);
                acc[ct] = __builtin_amdgcn_mfma_f32_16x16x32_bf16(a, b, acc[ct], 0, 0, 0);
            }
        }
        #pragma unroll
        for (int ct = 0; ct < 4; ct++) {
            #pragma unroll
            for (int r = 0; r < 4; r++)
                myH[(kq * 4 + r) * SH + ct * 16 + col] =
                    f2bf(fmaxf(acc[ct][r] + b1r[ct], 0.0f));
        }
        __builtin_amdgcn_wave_barrier();

        // ---- GEMM2: 16x64 @ 64x64 (B in registers) ----
        f32x4 m[4] = {{0,0,0,0},{0,0,0,0},{0,0,0,0},{0,0,0,0}};
        #pragma unroll
        for (int ks = 0; ks < 2; ks++) {
            int ko = ks * 32 + kq * 8;
            bf16x8 a = lds_frag(&myH[col * SH + ko]);
            #pragma unroll
            for (int ct = 0; ct < 4; ct++)
                m[ct] = __builtin_amdgcn_mfma_f32_16x16x32_bf16(
                    a, __builtin_bit_cast(bf16x8, w2f[ks * 4 + ct]), m[ct], 0, 0, 0);
        }
        __builtin_amdgcn_wave_barrier();   // LDS reads done before next commit

        // ---- in-register row reduction (mask pad rows); +b2 per valid row ----
        #pragma unroll
        for (int ct = 0; ct < 4; ct++) {
            float ssum = 0.0f;
            #pragma unroll
            for (int r = 0; r < 4; r++) {
                float v = m[ct][r] + b2r[ct];
                ssum += ((kq * 4 + r) < rem) ? v : 0.0f;
            }
            ssum += __shfl_xor(ssum, 16);  // fold kq bit 0
            ssum += __shfl_xor(ssum, 32);  // fold kq bit 1
            aggv[ct] += ssum;
        }

        if (last) {
            // finalize node A: coalesced 128B bf16 store
            const float scale = 1.0f / ((float)dgA + 1e-6f);
            float vout = (kq == 0) ? aggv[0] : (kq == 1) ? aggv[1]
                       : (kq == 2) ? aggv[2] : aggv[3];
            agg[(size_t)nodeA * 64 + lane] = f2bf(vout * scale);
            if (nodeB >= N_NODES) break;
            aggv[0] = aggv[1] = aggv[2] = aggv[3] = 0.f;

            // shift pipeline: A <- B (meta + dst row resident), B <- C
            nodeA = nodeB; baseA = baseB; dgA = dgB; g0 = 0;
            d0A = d0B; d1A = d1B;
            nodeB = nodeC; baseB = pC0; dgB = pC1 - pC0;   // pC loaded >=1 node ago
            while (dgB == 0 && nodeB < N_NODES) {          // ~never
                nodeB += TW;
                int ix = nodeB < N_NODES ? nodeB : N_NODES;
                baseB = ofs[ix]; dgB = ofs[ix + 1] - baseB;
            }
            nodeC = nodeB + TW;
            {
                int ix = nodeC < N_NODES ? nodeC : N_NODES;
                pC0 = ofs[ix]; pC1 = ofs[ix + 1];          // issue for next shift
            }
            int nbs2 = nodeB < N_NODES ? nodeB : 0;
            const u16x8* pdB2 = (const u16x8*)(xb + (size_t)nbs2 * 64);
            d0B = pdB2[2 * q]; d1B = pdB2[2 * q + 1];      // lands within >=1 group
        } else {
            g0 += 16;
        }

        // rotate prefetched gather into current
        gx0 = gxN0; gx1 = gxN1; fe = feN;
    }
}

// ---- node update: [64 nodes x 128] x [128 x 64] per block, coalesced rows ----
#define NSA 136
__global__ __launch_bounds__(256, 4) void node_kernel(
    const float* __restrict__ x,
    const unsigned short* __restrict__ agg,   // bf16, already normalized
    const unsigned short* __restrict__ Wut,
    const float* __restrict__ bu,
    float* __restrict__ out)
{
    __shared__ __align__(16) unsigned short sA [64 * NSA];
    __shared__ __align__(16) unsigned short sWu[64 * NSA];
    const int t = threadIdx.x, lane = t & 63, w = t >> 6;
    const int n0 = blockIdx.x * 64;

    #pragma unroll
    for (int i = 0; i < 4; i++) {
        int c = t + i * 256;
        int n = c / 16, k8 = c % 16;
        *(u16x8*)&sWu[n * NSA + k8 * 8] = *(const u16x8*)&Wut[c * 8];
    }
    {
        const int nl = t >> 2, q = t & 3;
        const int n = n0 + nl;
        unsigned short* row = sA + nl * NSA;
        if (n < N_NODES) {
            const float4* px = (const float4*)(x + (size_t)n * 64);
            cvt16v(row + q * 16, px[q*4], px[q*4+1], px[q*4+2], px[q*4+3]);
            const u16x8* pa = (const u16x8*)(agg + (size_t)n * 64);
            *(u16x8*)(row + 64 + q * 16)     = pa[2 * q];
            *(u16x8*)(row + 64 + q * 16 + 8) = pa[2 * q + 1];
        } else {
            u16x8 z = {0,0,0,0,0,0,0,0};
            *(u16x8*)&row[q * 16]          = z;
            *(u16x8*)&row[q * 16 + 8]      = z;
            *(u16x8*)&row[64 + q * 16]     = z;
            *(u16x8*)&row[64 + q * 16 + 8] = z;
        }
    }
    __syncthreads();

    const int col = lane & 15, kq = lane >> 4;
    const int arow = w * 16 + col;
    f32x4 acc[4] = {{0,0,0,0},{0,0,0,0},{0,0,0,0},{0,0,0,0}};
    #pragma unroll
    for (int ks = 0; ks < 4; ks++) {
        int ko = ks * 32 + kq * 8;
        bf16x8 a = lds_frag(&sA[arow * NSA + ko]);
        #pragma unroll
        for (int ct = 0; ct < 4; ct++) {
            bf16x8 b = lds_frag(&sWu[(ct * 16 + col) * NSA + ko]);
            acc[ct] = __builtin_amdgcn_mfma_f32_16x16x32_bf16(a, b, acc[ct], 0, 0, 0);
        }
    }
    #pragma unroll
    for (int ct = 0; ct < 4; ct++) {
        float bb = bu[ct * 16 + col];
        #pragma unroll
        for (int r = 0; r < 4; r++) {
            int row = w * 16 + kq * 4 + r;
            int n = n0 + row;
            if (n < N_NODES) {
                int c2 = ct * 16 + col;
                float xa = x[(size_t)n * 64 + c2];          // exact fp32 residual
                out[(size_t)n * 64 + c2] = xa + fmaxf(acc[ct][r] + bb, 0.0f);
            }
        }
    }
}

extern "C" void kernel_launch(void* const* d_in, const int* in_sizes, int n_in,
                              void* d_out, int out_size, void* d_ws, size_t ws_size,
                              hipStream_t stream) {
    const float* x  = (const float*)d_in[0];
    const int*   ei = (const int*)  d_in[1];
    const float* ea = (const float*)d_in[2];
    const float* W1 = (const float*)d_in[3];
    const float* b1 = (const float*)d_in[4];
    const float* W2 = (const float*)d_in[5];
    const float* b2 = (const float*)d_in[6];
    const float* Wu = (const float*)d_in[7];
    const float* bu = (const float*)d_in[8];
    float* out = (float*)d_out;

    // workspace layout (~40 MB total)
    unsigned short* agg = (unsigned short*)d_ws;                 // [N][64] bf16
    int* deg  = (int*)(agg + (size_t)N_NODES * HIDDEN);          // [N]
    int* ofs  = deg + N_NODES;                                   // [N+2]
    int* cur  = ofs + (N_NODES + 2);                             // [N]
    int* bsum = cur + N_NODES;                                   // [512]
    long long* elist = (long long*)(bsum + 512);                 // [E+16] (eid<<32)|src
    unsigned short* W1t = (unsigned short*)(elist + N_EDGES + 16); // [64][160]
    unsigned short* W2t = W1t + 64 * 160;                        // [64][64]
    unsigned short* Wut = W2t + 64 * 64;                         // [64][128]
    unsigned short* xb  = Wut + 64 * 128;                        // [N][64] bf16

    // zero agg (for deg==0 nodes) + deg (histogram) in one contiguous memset
    hipMemsetAsync(d_ws, 0,
                   (size_t)N_NODES * HIDDEN * sizeof(unsigned short)
                   + (size_t)N_NODES * sizeof(int), stream);

    prep_kernel<<<512, 256, 0, stream>>>(W1, W2, Wu, x, ei, W1t, W2t, Wut, xb, deg);
    scan1_kernel<<<NB1, 256, 0, stream>>>(deg, ofs, bsum);
    scan2_kernel<<<1, 512, 0, stream>>>(bsum);
    scan3_kernel<<<NB1, 256, 0, stream>>>(ofs, bsum, cur);
    fill_kernel<<<1024, 256, 0, stream>>>(ei, cur, elist);
    agg_kernel<<<AGG_BLOCKS, 256, 0, stream>>>(xb, ea, elist, ofs,
                                               W1t, W2t, b1, b2, agg);
    node_kernel<<<(N_NODES + 63) / 64, 256, 0, stream>>>(x, agg, Wut, bu, out);
}